// Round 7
// baseline (310.924 us; speedup 1.0000x reference)
//
#include <hip/hip_runtime.h>
#include <hip/hip_bf16.h>
#include <cstdint>

// ---------------------------------------------------------------------------
// LinearMultiHeadAttention: B=4, S=4096, D_MODEL=1024, H=16, Dk=64
// Gram-path:
//   G[b]  = x[b]^T x[b]     (SYMMETRIC: upper-triangle tiles only, split-K=4)
//   H[b]  = Wk @ G[b]
//   kv[b,h] = H_h @ Wv_h^T
//   E_t[b][j][hd] = scale*sum_e kv*Wo
//   F[b]  = E_t[b] @ Wq
//   out   = x @ F[b]^T
// R13 vs R12:
//   - prep v2: measured 46.8us @ 2.4TB/s (G7 ILP failure: load/store
//     interleave -> 1 load in flight). Now ALL loads issued upfront into
//     registers (8 float4/thread = 128B in flight), then convert+store,
//     then transpose-read. x-tile 64Sx128D (2048 blocks); W-casts 8
//     loads/thread (256 blocks). Target ~30us.
//   - gram: fin-proven 3-buf single-barrier counted-vmcnt ledger with
//     launch_bounds(256,2) (R10's gram3 regression = (256,3) VGPR-84 spill;
//     cap is now 256). LDS 3x16KB -> 3 blocks/CU.
//   - fin/H/F/kvblk/make_E8/reduce_g unchanged from R12.
// ---------------------------------------------------------------------------

typedef __bf16 bf16x8 __attribute__((ext_vector_type(8)));
typedef float f32x4 __attribute__((ext_vector_type(4)));
typedef unsigned short ushort_t;

__device__ inline void gld_lds16(const void* g, void* l) {
    __builtin_amdgcn_global_load_lds(
        (const __attribute__((address_space(1))) unsigned int*)g,
        (__attribute__((address_space(3))) unsigned int*)l,
        16, 0, 0);
}

__device__ inline ushort_t f2bf(float f) {
    uint32_t u = __float_as_uint(f);
    uint32_t r = (u + 0x7fffu + ((u >> 16) & 1u)) >> 16;
    return (ushort_t)r;
}
__device__ inline float bf2f(ushort_t u) {
    return __uint_as_float((uint32_t)u << 16);
}

// ---------------------------------------------------------------------------
// prep v2: one kernel, three roles by blockIdx.x (grid 2560):
//   [0,2048)    x-role: 64S x 128D tile -> xb + xbT. 8 upfront float4 loads.
//   [2048,2304) Wk|Wv plain cast, 8192 floats/block, 8 upfront loads.
//   [2304,2560) Wq transpose 64x64, 4 upfront loads.
// ---------------------------------------------------------------------------
__global__ __launch_bounds__(256)
void prep(const float* __restrict__ x, const float* __restrict__ Wk,
          const float* __restrict__ Wv, const float* __restrict__ Wq,
          ushort_t* __restrict__ xb, ushort_t* __restrict__ xbT,
          ushort_t* __restrict__ wkv, ushort_t* __restrict__ wqT)
{
    __shared__ ushort_t lt[2][64 * 66];
    const int id = blockIdx.x;
    const int t  = threadIdx.x;

    if (id < 2048) {
        // ---- x role: s0 in 256 steps of 64, i0 in 8 steps of 128 ----
        const int s0 = (id & 255) * 64;
        const int i0 = (id >> 8) * 128;

        float4 f[8];
#pragma unroll
        for (int c = 0; c < 8; ++c) {
            const int idx = c * 256 + t;          // 2048 slots = 64r x 32 f4
            const int r  = idx >> 5;              // s-row 0..63
            const int c4 = (idx & 31) * 4;        // D-col 0..124
            f[c] = *(const float4*)&x[(size_t)(s0 + r) * 1024 + i0 + c4];
        }
#pragma unroll
        for (int c = 0; c < 8; ++c) {
            const int idx = c * 256 + t;
            const int r  = idx >> 5;
            const int c4 = (idx & 31) * 4;
            ushort4 o;
            o.x = f2bf(f[c].x); o.y = f2bf(f[c].y);
            o.z = f2bf(f[c].z); o.w = f2bf(f[c].w);
            *(ushort4*)&xb[(size_t)(s0 + r) * 1024 + i0 + c4] = o;
            const int half = c4 >> 6;
            const int cc   = c4 & 63;
            *(uint32_t*)&lt[half][r * 66 + cc]     = (uint32_t)o.x | ((uint32_t)o.y << 16);
            *(uint32_t*)&lt[half][r * 66 + cc + 2] = (uint32_t)o.z | ((uint32_t)o.w << 16);
        }
        __syncthreads();
#pragma unroll
        for (int c = 0; c < 8; ++c) {
            const int idx  = c * 256 + t;         // 2048 slots = 128 rows x 16 grp
            const int rig  = idx >> 4;            // xbT row (D) 0..127
            const int s4   = (idx & 15) * 4;      // s-col 0..60
            const int half = rig >> 6;
            const int ri   = rig & 63;
            ushort4 o;
            o.x = lt[half][(s4 + 0) * 66 + ri];
            o.y = lt[half][(s4 + 1) * 66 + ri];
            o.z = lt[half][(s4 + 2) * 66 + ri];
            o.w = lt[half][(s4 + 3) * 66 + ri];
            *(ushort4*)&xbT[(size_t)(i0 + rig) * 16384 + s0 + s4] = o;
        }
        return;
    }

    if (id < 2304) {
        // ---- Wk/Wv plain cast: 8192 floats per block; 1M boundary is
        // 8192-aligned so a block never straddles Wk|Wv ----
        const int q  = id - 2048;                 // 0..255
        const int qq = (q < 128) ? q : q - 128;
        const float* src = (q < 128) ? Wk : Wv;
        float4 f[8];
#pragma unroll
        for (int c = 0; c < 8; ++c)
            f[c] = *(const float4*)&src[(size_t)qq * 8192 + c * 1024 + t * 4];
        ushort_t* d = wkv + (size_t)q * 8192;
#pragma unroll
        for (int c = 0; c < 8; ++c) {
            ushort4 o;
            o.x = f2bf(f[c].x); o.y = f2bf(f[c].y);
            o.z = f2bf(f[c].z); o.w = f2bf(f[c].w);
            *(ushort4*)&d[c * 1024 + t * 4] = o;
        }
        return;
    }

    // ---- Wq transpose role (64x64 tile) ----
    const int id2 = id - 2304;                    // 0..255
    const int r0 = (id2 >> 4) * 64;
    const int c0 = (id2 & 15) * 64;
    float4 f[4];
#pragma unroll
    for (int c = 0; c < 4; ++c) {
        const int idx = c * 256 + t;
        const int r = idx >> 4, c4 = (idx & 15) * 4;
        f[c] = *(const float4*)&Wq[(size_t)(r0 + r) * 1024 + c0 + c4];
    }
#pragma unroll
    for (int c = 0; c < 4; ++c) {
        const int idx = c * 256 + t;
        const int r = idx >> 4, c4 = (idx & 15) * 4;
        ushort4 o;
        o.x = f2bf(f[c].x); o.y = f2bf(f[c].y);
        o.z = f2bf(f[c].z); o.w = f2bf(f[c].w);
        *(uint32_t*)&lt[0][r * 66 + c4]     = (uint32_t)o.x | ((uint32_t)o.y << 16);
        *(uint32_t*)&lt[0][r * 66 + c4 + 2] = (uint32_t)o.z | ((uint32_t)o.w << 16);
    }
    __syncthreads();
#pragma unroll
    for (int c = 0; c < 4; ++c) {
        const int idx = c * 256 + t;
        const int ri = idx >> 4, s4 = (idx & 15) * 4;
        ushort4 o;
        o.x = lt[0][(s4 + 0) * 66 + ri];
        o.y = lt[0][(s4 + 1) * 66 + ri];
        o.z = lt[0][(s4 + 2) * 66 + ri];
        o.w = lt[0][(s4 + 3) * 66 + ri];
        *(ushort4*)&wqT[(size_t)(c0 + ri) * 1024 + r0 + s4] = o;
    }
}

// ---------------------------------------------------------------------------
// C = A @ B^T. 128x64 tile, BK=32, XOR-swizzled LDS. 256 thr = 4 waves (2Mx2N),
// per-wave 64x32 out. 512 blocks for 1024x1024 GEMMs -> 2/CU resident.
// ---------------------------------------------------------------------------
template <typename OutT>
__global__ __launch_bounds__(256, 4)
void gemm_bt_n64(const ushort_t* __restrict__ A, int lda, long strideA,
                 const ushort_t* __restrict__ B, int ldb, long strideB,
                 OutT* __restrict__ C0, int ldc0, long strideC0, int K)
{
    __shared__ ushort_t lA[128 * 32];
    __shared__ ushort_t lB[64 * 32];

    const int t    = threadIdx.x;
    const int lane = t & 63;
    const int wid  = t >> 6;          // 0..3
    const int z    = blockIdx.z;

    A += (size_t)z * strideA;
    B += (size_t)z * strideB;

    const int m0 = blockIdx.x * 128;
    const int n0 = blockIdx.y * 64;

    const int wm = (wid >> 1) * 64;   // 0,64
    const int wn = (wid & 1) * 32;    // 0,32
    const int mr = lane & 15;
    const int q4 = lane >> 4;

    const int row_a = t >> 2;                       // 0..63
    const int seg   = ((t & 3) ^ ((t >> 3) & 3)) * 8;
    const int csw   = (q4 ^ ((mr >> 1) & 3)) * 16;

    f32x4 acc[4][2] = {};

    for (int k0 = 0; k0 < K; k0 += 32) {
        __syncthreads();
        gld_lds16(A + (size_t)(m0 + row_a) * lda + k0 + seg,      (char*)lA + wid * 1024);
        gld_lds16(A + (size_t)(m0 + 64 + row_a) * lda + k0 + seg, (char*)lA + 4096 + wid * 1024);
        gld_lds16(B + (size_t)(n0 + row_a) * ldb + k0 + seg,      (char*)lB + wid * 1024);
        __syncthreads();

        bf16x8 af[4], bf[2];
#pragma unroll
        for (int i = 0; i < 4; ++i)
            af[i] = *(const bf16x8*)((const char*)lA + (wm + i * 16 + mr) * 64 + csw);
#pragma unroll
        for (int j = 0; j < 2; ++j)
            bf[j] = *(const bf16x8*)((const char*)lB + (wn + j * 16 + mr) * 64 + csw);
#pragma unroll
        for (int i = 0; i < 4; ++i)
#pragma unroll
            for (int j = 0; j < 2; ++j)
                acc[i][j] = __builtin_amdgcn_mfma_f32_16x16x32_bf16(af[i], bf[j], acc[i][j], 0, 0, 0);
    }

    OutT* Cw = C0 + (size_t)z * strideC0;
#pragma unroll
    for (int i = 0; i < 4; ++i) {
        const int rbase = m0 + wm + i * 16 + q4 * 4;
#pragma unroll
        for (int j = 0; j < 2; ++j) {
            const int col = n0 + wn + j * 16 + mr;
#pragma unroll
            for (int r = 0; r < 4; ++r) {
                const float v = acc[i][j][r];
                const size_t off = (size_t)(rbase + r) * ldc0 + col;
                if constexpr (sizeof(OutT) == 2) Cw[off] = f2bf(v);
                else                             Cw[off] = v;
            }
        }
    }
}

// ---------------------------------------------------------------------------
// FINAL GEMM: C = A @ B^T fp32. 256x128 tile, BK=32, 4 waves, wave = 128x64
// (acc[8][4], 32 MFMA / 12 ds_read). TRIPLE-buffered LDS (3x24KB=72KB) ->
// 2 blocks/CU. One s_barrier per kt, counted-vmcnt ledger:
//   prologue stage(0),stage(1), vmcnt(6), BAR.
//   iter kt: rd 12 frags from buf[cur] | stage(kt+2)->buf[cur+2] | lgkm0 |
//            32 MFMA | vmcnt(6) (drain kt+1, leave kt+2) | BAR.
// + XCD-bijective remap (FETCH -14%).
// ---------------------------------------------------------------------------
__global__ __launch_bounds__(256, 2)
void gemm_fin(const ushort_t* __restrict__ A, int lda, long strideA,
              const ushort_t* __restrict__ B, int ldb, long strideB,
              float* __restrict__ C, int ldc, long strideC, int K)
{
    __shared__ char lds[73728];      // 3 x 24576 (A@0..16K, B@16K..24K)

    const int t    = threadIdx.x;    // 256
    const int lane = t & 63;
    const int wid  = t >> 6;         // 0..3

    const int L  = blockIdx.x + (blockIdx.y << 4) + (blockIdx.z << 7);
    const int w  = ((L & 7) << 6) + (L >> 3);
    const int bx = w & 15, by = (w >> 4) & 7, z = w >> 7;

    A += (size_t)z * strideA;
    B += (size_t)z * strideB;

    const int m0 = bx * 256;
    const int n0 = by * 128;

    const int wr = wid >> 1;         // 0..1: 128-row half of A-tile
    const int wn = wid & 1;          // 0..1: 64-col half of B-tile
    const int mr = lane & 15;
    const int q4 = lane >> 4;

    const int NT = K >> 5;           // 32

    const int row_a = t >> 2;                         // 0..63
    const int seg   = ((t & 3) ^ ((t >> 3) & 3)) * 8; // inverse-swizzled src col
    const int csw   = (q4 ^ ((mr >> 1) & 3)) * 16;    // swizzled read col

    auto stage = [&](int tgt, int bsel) {
        if (tgt >= NT) return;
        char* base = lds + bsel * 24576 + wid * 1024;
        const ushort_t* gA = A + (size_t)(m0 + row_a) * lda + tgt * 32 + seg;
        gld_lds16(gA,                          base);          // rows   0..63
        gld_lds16(gA + ((size_t)lda << 6),     base + 4096);   // rows  64..127
        gld_lds16(gA + ((size_t)lda << 7),     base + 8192);   // rows 128..191
        gld_lds16(gA + (size_t)lda * 192,      base + 12288);  // rows 192..255
        const ushort_t* gB = B + (size_t)(n0 + row_a) * ldb + tgt * 32 + seg;
        gld_lds16(gB,                          base + 16384);  // rows   0..63
        gld_lds16(gB + ((size_t)ldb << 6),     base + 20480);  // rows  64..127
    };

    bf16x8 af[8], bf[4];
    f32x4 acc[8][4] = {};

    // prologue
    stage(0, 0);
    stage(1, 1);
    asm volatile("s_waitcnt vmcnt(6)" ::: "memory");
    __builtin_amdgcn_s_barrier();

    int cur = 0;
    for (int kt = 0; kt < NT; ++kt) {
        const char* buf = lds + cur * 24576;
#pragma unroll
        for (int i = 0; i < 8; ++i)
            af[i] = *(const bf16x8*)(buf + (wr * 128 + i * 16 + mr) * 64 + csw);
#pragma unroll
        for (int j = 0; j < 4; ++j)
            bf[j] = *(const bf16x8*)(buf + 16384 + (wn * 64 + j * 16 + mr) * 64 + csw);

        int b2 = cur + 2; if (b2 >= 3) b2 -= 3;
        stage(kt + 2, b2);

        asm volatile("s_waitcnt lgkmcnt(0)" ::: "memory");
        __builtin_amdgcn_sched_barrier(0);
        __builtin_amdgcn_s_setprio(1);
#pragma unroll
        for (int i = 0; i < 8; ++i)
#pragma unroll
            for (int j = 0; j < 4; ++j)
                acc[i][j] = __builtin_amdgcn_mfma_f32_16x16x32_bf16(
                    af[i], bf[j], acc[i][j], 0, 0, 0);
        __builtin_amdgcn_s_setprio(0);
        __builtin_amdgcn_sched_barrier(0);

        if (kt + 2 < NT)       asm volatile("s_waitcnt vmcnt(6)" ::: "memory");
        else if (kt + 2 == NT) asm volatile("s_waitcnt vmcnt(0)" ::: "memory");
        __builtin_amdgcn_s_barrier();
        if (++cur == 3) cur = 0;
    }

    float* Cw = C + (size_t)z * strideC;
#pragma unroll
    for (int i = 0; i < 8; ++i) {
        const int rbase = m0 + wr * 128 + i * 16 + q4 * 4;
#pragma unroll
        for (int j = 0; j < 4; ++j) {
            const int col = n0 + wn * 64 + j * 16 + mr;
#pragma unroll
            for (int r = 0; r < 4; ++r)
                Cw[(size_t)(rbase + r) * ldc + col] = acc[i][j][r];
        }
    }
}

// ---------------------------------------------------------------------------
// Gram GEMM (R13): fin-proven 3-buf single-barrier counted-vmcnt ledger at
// 128^2, 4-load stages, vmcnt(4) steady, launch_bounds(256,2) (no VGPR cap
// below need -- R10's (256,3) cap caused the spill regression).
// LDS 3x16KB = 48KB -> 3 blocks/CU. grid (16 z fastest, 36 triangle tiles).
// ---------------------------------------------------------------------------
__global__ __launch_bounds__(256, 2)
void gemm_gram3(const ushort_t* __restrict__ X, ushort_t* __restrict__ Gp)
{
    __shared__ char lds[49152];      // 3 x 16384 (A@0..8K, B@8K..16K)

    const int t    = threadIdx.x;
    const int lane = t & 63;
    const int wid  = t >> 6;

    const int z  = blockIdx.x;
    const int bb = z >> 2, ks = z & 3;

    int ti = 0, rem = blockIdx.y;
    while (rem >= 8 - ti) { rem -= 8 - ti; ++ti; }
    const int tj = ti + rem;
    const int m0 = ti * 128;
    const int n0 = tj * 128;

    const ushort_t* A = X + (size_t)bb * 4096 + (size_t)ks * 1024;
    const int NT = 32;               // K = 1024, BK = 32

    const int wm = (wid >> 1) * 64;
    const int wn = (wid & 1) * 64;
    const int mr = lane & 15;
    const int q4 = lane >> 4;

    const int row_a = t >> 2;
    const int seg   = ((t & 3) ^ ((t >> 3) & 3)) * 8;
    const int csw   = (q4 ^ ((mr >> 1) & 3)) * 16;

    auto stage = [&](int tgt, int bsel) {
        if (tgt >= NT) return;
        char* base = lds + bsel * 16384 + wid * 1024;
        const ushort_t* gA = A + (size_t)(m0 + row_a) * 16384 + tgt * 32 + seg;
        gld_lds16(gA,                        base);
        gld_lds16(gA + ((size_t)16384 << 6), base + 4096);
        const ushort_t* gB = A + (size_t)(n0 + row_a) * 16384 + tgt * 32 + seg;
        gld_lds16(gB,                        base + 8192);
        gld_lds16(gB + ((size_t)16384 << 6), base + 12288);
    };

    bf16x8 af[4], bf[4];
    f32x4 acc[4][4] = {};

    stage(0, 0);
    stage(1, 1);
    asm volatile("s_waitcnt vmcnt(4)" ::: "memory");
    __builtin_amdgcn_s_barrier();

    int cur = 0;
    for (int kt = 0; kt < NT; ++kt) {
        const char* buf = lds + cur * 16384;
#pragma unroll
        for (int i = 0; i < 4; ++i)
            af[i] = *(const bf16x8*)(buf + (wm + i * 16 + mr) * 64 + csw);
#pragma unroll
        for (int j = 0; j < 4; ++j)
            bf[j] = *(const bf16x8*)(buf + 8192 + (wn + j * 16 + mr) * 64 + csw);

        int b2 = cur + 2; if (b2 >= 3) b2 -= 3;
        stage(kt + 2, b2);

        asm volatile("s_waitcnt lgkmcnt(0)" ::: "memory");
        __builtin_amdgcn_sched_barrier(0);
        __builtin_amdgcn_s_setprio(1);
#pragma unroll
        for (int i = 0; i < 4; ++i)
#pragma unroll
            for (int j = 0; j < 4; ++j)
                acc[i][j] = __builtin_amdgcn_mfma_f32_16x16x32_bf16(
                    af[i], bf[j], acc[i][j], 0, 0, 0);
        __builtin_amdgcn_s_setprio(0);
        __builtin_amdgcn_sched_barrier(0);

        if (kt + 2 < NT)       asm volatile("s_waitcnt vmcnt(4)" ::: "memory");
        else if (kt + 2 == NT) asm volatile("s_waitcnt vmcnt(0)" ::: "memory");
        __builtin_amdgcn_s_barrier();
        if (++cur == 3) cur = 0;
    }

    ushort_t* Cw = Gp + ((size_t)z << 20);
#pragma unroll
    for (int i = 0; i < 4; ++i) {
        const int rbase = m0 + wm + i * 16 + q4 * 4;
#pragma unroll
        for (int j = 0; j < 4; ++j) {
            const int col = n0 + wn + j * 16 + mr;
#pragma unroll
            for (int r = 0; r < 4; ++r)
                Cw[(size_t)(rbase + r) * 1024 + col] = f2bf(acc[i][j][r]);
        }
    }
}

// ---------------------------------------------------------------------------
// reduce_g_t: G[b][tr*64+r][tc*64+c] = sum_ks Gp[b*4+ks] at source 64-tile
// (sr,sc)=(min,max). Lower tiles transpose through LDS (pitch 65).
// ---------------------------------------------------------------------------
__global__ __launch_bounds__(256)
void reduce_g_t(const ushort_t* __restrict__ Gp, ushort_t* __restrict__ G)
{
    __shared__ float acc[64 * 65];

    const int t  = threadIdx.x;
    const int b  = blockIdx.y;
    const int tr = blockIdx.x >> 4, tc = blockIdx.x & 15;
    const int sr = (tr <= tc) ? tr : tc;
    const int sc = (tr <= tc) ? tc : tr;
    const bool flip = tr > tc;

#pragma unroll
    for (int p = 0; p < 4; ++p) {
        const int idx = p * 256 + t;
        const int r = idx >> 4, c = (idx & 15) * 4;
        float a0 = 0.f, a1 = 0.f, a2 = 0.f, a3 = 0.f;
#pragma unroll
        for (int ksl = 0; ksl < 4; ++ksl) {
            const ushort4 u = *(const ushort4*)&Gp[((size_t)(b * 4 + ksl) << 20)
                                                   + (size_t)(sr * 64 + r) * 1024 + sc * 64 + c];
            a0 += bf2f(u.x); a1 += bf2f(u.y); a2 += bf2f(u.z); a3 += bf2f(u.w);
        }
        acc[r * 65 + c + 0] = a0;
        acc[r * 65 + c + 1] = a1;
        acc[r * 65 + c + 2] = a2;
        acc[r * 65 + c + 3] = a3;
    }
    __syncthreads();

#pragma unroll
    for (int p = 0; p < 4; ++p) {
        const int idx = p * 256 + t;
        const int r = idx >> 4, c = (idx & 15) * 4;
        float v0, v1, v2, v3;
        if (flip) {
            v0 = acc[(c + 0) * 65 + r];
            v1 = acc[(c + 1) * 65 + r];
            v2 = acc[(c + 2) * 65 + r];
            v3 = acc[(c + 3) * 65 + r];
        } else {
            v0 = acc[r * 65 + c + 0];
            v1 = acc[r * 65 + c + 1];
            v2 = acc[r * 65 + c + 2];
            v3 = acc[r * 65 + c + 3];
        }
        ushort4 o;
        o.x = f2bf(v0); o.y = f2bf(v1); o.z = f2bf(v2); o.w = f2bf(v3);
        *(ushort4*)&G[((size_t)b << 20) + (size_t)(tr * 64 + r) * 1024 + tc * 64 + c] = o;
    }
}

// ---------------------------------------------------------------------------
// kv partials: KVp[is][bh][d][e] = sum_{i-slice} H[b][h64+d][i]*Wv[h64+e][i]
// ---------------------------------------------------------------------------
__global__ __launch_bounds__(256)
void kvblk(const ushort_t* __restrict__ H, const ushort_t* __restrict__ Wv,
           float* __restrict__ KVp)
{
    __shared__ ushort_t sH[64 * 132];
    __shared__ ushort_t sV[64 * 132];

    const int t  = threadIdx.x;
    const int is = blockIdx.x;
    const int bh = blockIdx.y;
    const int b  = bh >> 4, h = bh & 15;

    const ushort_t* Hp = H + ((size_t)b << 20) + (size_t)(h * 64) * 1024 + is * 128;
    const ushort_t* Vp = Wv + (size_t)(h * 64) * 1024 + is * 128;

#pragma unroll
    for (int i2 = 0; i2 < 8; ++i2) {
        const int ci = i2 * 256 + t;
        const int r = ci >> 5, c = (ci & 31) * 4;
        *(uint2*)&sH[r * 132 + c] = *(const uint2*)&Hp[(size_t)r * 1024 + c];
        *(uint2*)&sV[r * 132 + c] = *(const uint2*)&Vp[(size_t)r * 1024 + c];
    }
    __syncthreads();

    const int d0 = (t >> 4) * 4;
    const int e0 = (t & 15) * 4;
    float acc[4][4] = {};

#pragma unroll 2
    for (int i4 = 0; i4 < 128; i4 += 4) {
        uint2 hu[4], vu[4];
#pragma unroll
        for (int j = 0; j < 4; ++j) {
            hu[j] = *(const uint2*)&sH[(d0 + j) * 132 + i4];
            vu[j] = *(const uint2*)&sV[(e0 + j) * 132 + i4];
        }
        float hf[4][4], vf[4][4];
#pragma unroll
        for (int j = 0; j < 4; ++j) {
            hf[j][0] = __uint_as_float(hu[j].x << 16);
            hf[j][1] = __uint_as_float(hu[j].x & 0xffff0000u);
            hf[j][2] = __uint_as_float(hu[j].y << 16);
            hf[j][3] = __uint_as_float(hu[j].y & 0xffff0000u);
            vf[j][0] = __uint_as_float(vu[j].x << 16);
            vf[j][1] = __uint_as_float(vu[j].x & 0xffff0000u);
            vf[j][2] = __uint_as_float(vu[j].y << 16);
            vf[j][3] = __uint_as_float(vu[j].y & 0xffff0000u);
        }
#pragma unroll
        for (int ii = 0; ii < 4; ++ii)
#pragma unroll
            for (int di = 0; di < 4; ++di)
#pragma unroll
                for (int ej = 0; ej < 4; ++ej)
                    acc[di][ej] += hf[di][ii] * vf[ej][ii];
    }

    float* outp = KVp + ((size_t)(is * 64 + bh)) * 4096;
#pragma unroll
    for (int i = 0; i < 4; ++i) {
        float4 o; o.x = acc[i][0]; o.y = acc[i][1]; o.z = acc[i][2]; o.w = acc[i][3];
        *(float4*)&outp[(d0 + i) * 64 + e0] = o;
    }
}

// ---------------------------------------------------------------------------
// make_E8: E_t[b][j][h*64+d] = scale * sum_e kv[b,h,d,e] * W_o[j, h*64+e]
// kv summed from the 8 kvblk partials during staging.
// ---------------------------------------------------------------------------
__global__ __launch_bounds__(256)
void make_E8(const float* __restrict__ KVp, const float* __restrict__ Wo,
             ushort_t* __restrict__ Et)
{
    __shared__ float skv[64 * 65];
    __shared__ float swo[64 * 65];

    const int t  = threadIdx.x;
    const int bh = blockIdx.y;
    const int b  = bh >> 4, h = bh & 15;
    const int j0 = blockIdx.x * 64;

#pragma unroll
    for (int i = 0; i < 4; ++i) {
        const int idx = t + i * 256;
        const int r = idx >> 4, c = (idx & 15) * 4;
        float4 f; f.x = 0.f; f.y = 0.f; f.z = 0.f; f.w = 0.f;
#pragma unroll
        for (int is = 0; is < 8; ++is) {
            const float4 p = *(const float4*)&KVp[((size_t)(is * 64 + bh)) * 4096
                                                  + r * 64 + c];
            f.x += p.x; f.y += p.y; f.z += p.z; f.w += p.w;
        }
        skv[r * 65 + c + 0] = f.x;
        skv[r * 65 + c + 1] = f.y;
        skv[r * 65 + c + 2] = f.z;
        skv[r * 65 + c + 3] = f.w;
        const float4 g = *(const float4*)&Wo[(size_t)(j0 + r) * 1024 + h * 64 + c];
        swo[r * 65 + c + 0] = g.x;
        swo[r * 65 + c + 1] = g.y;
        swo[r * 65 + c + 2] = g.z;
        swo[r * 65 + c + 3] = g.w;
    }
    __syncthreads();

    const int d0 = (t & 15) * 4;
#pragma unroll
    for (int pass = 0; pass < 4; ++pass) {
        const int jloc = (t >> 4) + pass * 16;
        float s0 = 0.f, s1 = 0.f, s2 = 0.f, s3 = 0.f;
        const float* wrow = &swo[jloc * 65];
#pragma unroll 8
        for (int e = 0; e < 64; ++e) {
            const float w = wrow[e];
            s0 += skv[(d0 + 0) * 65 + e] * w;
            s1 += skv[(d0 + 1) * 65 + e] * w;
            s2 += skv[(d0 + 2) * 65 + e] * w;
            s3 += skv[(d0 + 3) * 65 + e] * w;
        }
        ushort4 o;
        o.x = f2bf(s0 * 0.125f);
        o.y = f2bf(s1 * 0.125f);
        o.z = f2bf(s2 * 0.125f);
        o.w = f2bf(s3 * 0.125f);
        *(ushort4*)&Et[((size_t)b * 1024 + j0 + jloc) * 1024 + h * 64 + d0] = o;
    }
}

// ---------------------------------------------------------------------------

extern "C" void kernel_launch(void* const* d_in, const int* in_sizes, int n_in,
                              void* d_out, int out_size, void* d_ws, size_t ws_size,
                              hipStream_t stream)
{
    const float* x  = (const float*)d_in[0];
    const float* Wq = (const float*)d_in[1];
    const float* Wk = (const float*)d_in[2];
    const float* Wv = (const float*)d_in[3];
    const float* Wo = (const float*)d_in[4];
    float* out = (float*)d_out;

    const int B = 4, S = 4096, D = 1024;
    const long MB1 = 1048576;

    char* ws = (char*)d_ws;
    size_t off = 0;
    auto alloc = [&](size_t bytes) -> void* {
        void* p = ws + off;
        off += (bytes + 255) & ~(size_t)255;
        return p;
    };
    ushort_t* xb   = (ushort_t*)alloc((size_t)B * S * D * 2);      // 33.5 MB
    ushort_t* xbT  = (ushort_t*)alloc((size_t)D * B * S * 2);      // 33.5 MB
    ushort_t* wkv  = (ushort_t*)alloc((size_t)2 * D * D * 2);      // wk | wv
    ushort_t* wqT  = (ushort_t*)alloc((size_t)D * D * 2);
    ushort_t* Gb   = (ushort_t*)alloc((size_t)B * D * D * 2);      // 8.4 MB
    float*    kvp  = (float*)alloc((size_t)8 * 64 * 4096 * 4);     // 8.4 MB
    ushort_t* Fb   = (ushort_t*)alloc((size_t)B * D * D * 2);      // 8.4 MB
    char*     R1   = (char*)alloc((size_t)16 * MB1 * 2);           // 33.5 MB shared
    ushort_t* Gp = (ushort_t*)R1;                    // [16][1M] bf16 partials
    ushort_t* Hb = (ushort_t*)R1;                    // [4][1M] (Gp[0..7] dead after reduce)
    ushort_t* Et = (ushort_t*)(R1 + 8 * MB1 * 2);    // [4][1M] (Gp[8..15] dead after reduce)
    ushort_t* wkb = wkv;
    ushort_t* wvb = wkv + MB1;

    // all input casts in one dispatch (ILP-restructured)
    prep<<<dim3(2560), dim3(256), 0, stream>>>(x, Wk, Wv, Wq, xb, xbT, wkv, wqT);

    // G[b] = x^T x, symmetric: 36 upper-triangle 128-tiles, split-K=4, z fastest
    gemm_gram3<<<dim3(16, 36), dim3(256), 0, stream>>>(xbT, Gp);
    reduce_g_t<<<dim3(256, 4), dim3(256), 0, stream>>>(Gp, Gb);

    // H[b] = Wk @ G[b]  (G symmetric -> use as B directly); 512 blocks, 2/CU
    gemm_bt_n64<ushort_t><<<dim3(8, 16, 4), dim3(256), 0, stream>>>(
        wkb, D, 0, Gb, D, MB1, Hb, D, MB1, D);

    // kv[b,h] = H_h @ Wv_h^T (i-split 8 partials)
    kvblk<<<dim3(8, 64), dim3(256), 0, stream>>>(Hb, wvb, kvp);

    // E_t (sums the 8 partials inline)
    make_E8<<<dim3(16, 64), dim3(256), 0, stream>>>(kvp, Wo, Et);

    // F[b] = E_t[b] @ Wq; 512 blocks, 2/CU
    gemm_bt_n64<ushort_t><<<dim3(8, 16, 4), dim3(256), 0, stream>>>(
        Et, D, MB1, wqT, D, 0, Fb, D, (long)D * D, D);

    // out[b] = x[b] @ F[b]^T -> fp32: 256x128 3-buf + XCD remap
    gemm_fin<<<dim3(16, 8, 4), dim3(256), 0, stream>>>(
        xb, D, (long)S * D, Fb, D, (long)D * D, out, D, (long)S * D, D);
}

// Round 8
// 309.739 us; speedup vs baseline: 1.0038x; 1.0038x over previous
//
#include <hip/hip_runtime.h>
#include <hip/hip_bf16.h>
#include <cstdint>

// ---------------------------------------------------------------------------
// LinearMultiHeadAttention: B=4, S=4096, D_MODEL=1024, H=16, Dk=64
// Gram-path:
//   G[b]  = x[b]^T x[b]     (SYMMETRIC: upper-triangle tiles only, split-K=4)
//   H[b]  = Wk @ G[b]
//   kv[b,h] = H_h @ Wv_h^T
//   E_t[b][j][hd] = scale*sum_e kv*Wo
//   F[b]  = E_t[b] @ Wq
//   out   = x @ F[b]^T
// R14 vs R13: prep v3 -- WRITE-CONTIGUITY redesign. R13 falsified the ILP
// theory (8 upfront loads, 55% occ, VALU 7% -> still 2.4TB/s). Writes ran at
// 1.54TB/s because xbT wrote 128B chunks at 32KB stride (DRAM page thrash).
//   Role A [0,1024):    xb via [16s x 1024D] tiles -> 2KB-contiguous rows,
//                       ushort8 (16B) stores.
//   Role B [1024,2048): xbT via [512s x 32D] tiles + LDS transpose
//                       lt[32][522] (pad 10: <=2-way write banks, read
//                       conflict-free) -> 1KB-contiguous xbT rows.
//   Role C [2048,2304): Wk|Wv plain cast (8 upfront loads).
//   Role D [2304,2560): Wq 64x64 transpose (66-pitch, proven).
// Everything else identical to R13.
// ---------------------------------------------------------------------------

typedef __bf16 bf16x8 __attribute__((ext_vector_type(8)));
typedef float f32x4 __attribute__((ext_vector_type(4)));
typedef unsigned short ushort_t;
typedef unsigned short ushort8_t __attribute__((ext_vector_type(8)));

__device__ inline void gld_lds16(const void* g, void* l) {
    __builtin_amdgcn_global_load_lds(
        (const __attribute__((address_space(1))) unsigned int*)g,
        (__attribute__((address_space(3))) unsigned int*)l,
        16, 0, 0);
}

__device__ inline ushort_t f2bf(float f) {
    uint32_t u = __float_as_uint(f);
    uint32_t r = (u + 0x7fffu + ((u >> 16) & 1u)) >> 16;
    return (ushort_t)r;
}
__device__ inline float bf2f(ushort_t u) {
    return __uint_as_float((uint32_t)u << 16);
}

// ---------------------------------------------------------------------------
// prep v3 (grid 2560): see header comment for role map.
// ---------------------------------------------------------------------------
__global__ __launch_bounds__(256)
void prep(const float* __restrict__ x, const float* __restrict__ Wk,
          const float* __restrict__ Wv, const float* __restrict__ Wq,
          ushort_t* __restrict__ xb, ushort_t* __restrict__ xbT,
          ushort_t* __restrict__ wkv, ushort_t* __restrict__ wqT)
{
    __shared__ ushort_t lt[32 * 522];   // 33.4 KB (role B); role D reuses head
    const int id = blockIdx.x;
    const int t  = threadIdx.x;

    if (id < 1024) {
        // ---- Role A: xb, [16s x 1024D] tile, fully-contiguous row writes ----
        const int s0 = id * 16;
        float4 f[16];
#pragma unroll
        for (int c = 0; c < 8; ++c) {
            const int slot = c * 256 + t;              // 0..2047
            const int row  = slot >> 7;                // 0..15
            const int col8 = (slot & 127) * 8;         // 0..1016
            f[2 * c]     = *(const float4*)&x[(size_t)(s0 + row) * 1024 + col8];
            f[2 * c + 1] = *(const float4*)&x[(size_t)(s0 + row) * 1024 + col8 + 4];
        }
#pragma unroll
        for (int c = 0; c < 8; ++c) {
            const int slot = c * 256 + t;
            const int row  = slot >> 7;
            const int col8 = (slot & 127) * 8;
            ushort8_t o;
            o[0] = f2bf(f[2 * c].x);     o[1] = f2bf(f[2 * c].y);
            o[2] = f2bf(f[2 * c].z);     o[3] = f2bf(f[2 * c].w);
            o[4] = f2bf(f[2 * c + 1].x); o[5] = f2bf(f[2 * c + 1].y);
            o[6] = f2bf(f[2 * c + 1].z); o[7] = f2bf(f[2 * c + 1].w);
            *(ushort8_t*)&xb[(size_t)(s0 + row) * 1024 + col8] = o;
        }
        return;
    }

    if (id < 2048) {
        // ---- Role B: xbT, [512s x 32D] tile, LDS transpose, 1KB row writes --
        const int id2 = id - 1024;                     // 0..1023
        const int s0 = (id2 & 31) * 512;
        const int i0 = (id2 >> 5) * 32;

        float4 f[16];
#pragma unroll
        for (int c = 0; c < 16; ++c) {
            const int slot = c * 256 + t;              // 0..4095
            const int sl = slot >> 3;                  // s_loc 0..511
            const int d4 = (slot & 7) * 4;             // 0..28
            f[c] = *(const float4*)&x[(size_t)(s0 + sl) * 1024 + i0 + d4];
        }
#pragma unroll
        for (int c = 0; c < 16; ++c) {
            const int slot = c * 256 + t;
            const int sl = slot >> 3;
            const int d4 = (slot & 7) * 4;
            lt[(d4 + 0) * 522 + sl] = f2bf(f[c].x);
            lt[(d4 + 1) * 522 + sl] = f2bf(f[c].y);
            lt[(d4 + 2) * 522 + sl] = f2bf(f[c].z);
            lt[(d4 + 3) * 522 + sl] = f2bf(f[c].w);
        }
        __syncthreads();
#pragma unroll
        for (int c = 0; c < 8; ++c) {
            const int slot = c * 256 + t;              // 0..2047
            const int d  = slot >> 6;                  // 0..31
            const int s8 = (slot & 63) * 8;            // 0..504
            const ushort8_t v = *(const ushort8_t*)&lt[d * 522 + s8];
            *(ushort8_t*)&xbT[(size_t)(i0 + d) * 16384 + s0 + s8] = v;
        }
        return;
    }

    if (id < 2304) {
        // ---- Role C: Wk/Wv plain cast, 8192 floats/block ----
        const int q  = id - 2048;                      // 0..255
        const int qq = (q < 128) ? q : q - 128;
        const float* src = (q < 128) ? Wk : Wv;
        float4 f[8];
#pragma unroll
        for (int c = 0; c < 8; ++c)
            f[c] = *(const float4*)&src[(size_t)qq * 8192 + c * 1024 + t * 4];
        ushort_t* d = wkv + (size_t)q * 8192;
#pragma unroll
        for (int c = 0; c < 8; ++c) {
            ushort4 o;
            o.x = f2bf(f[c].x); o.y = f2bf(f[c].y);
            o.z = f2bf(f[c].z); o.w = f2bf(f[c].w);
            *(ushort4*)&d[c * 1024 + t * 4] = o;
        }
        return;
    }

    // ---- Role D: Wq transpose (64x64 tile, 66-pitch in lt head) ----
    const int id2 = id - 2304;                         // 0..255
    const int r0 = (id2 >> 4) * 64;
    const int c0 = (id2 & 15) * 64;
    float4 f[4];
#pragma unroll
    for (int c = 0; c < 4; ++c) {
        const int idx = c * 256 + t;
        const int r = idx >> 4, c4 = (idx & 15) * 4;
        f[c] = *(const float4*)&Wq[(size_t)(r0 + r) * 1024 + c0 + c4];
    }
#pragma unroll
    for (int c = 0; c < 4; ++c) {
        const int idx = c * 256 + t;
        const int r = idx >> 4, c4 = (idx & 15) * 4;
        ushort4 o;
        o.x = f2bf(f[c].x); o.y = f2bf(f[c].y);
        o.z = f2bf(f[c].z); o.w = f2bf(f[c].w);
        *(uint32_t*)&lt[r * 66 + c4]     = (uint32_t)o.x | ((uint32_t)o.y << 16);
        *(uint32_t*)&lt[r * 66 + c4 + 2] = (uint32_t)o.z | ((uint32_t)o.w << 16);
    }
    __syncthreads();
#pragma unroll
    for (int c = 0; c < 4; ++c) {
        const int idx = c * 256 + t;
        const int ri = idx >> 4, s4 = (idx & 15) * 4;
        ushort4 o;
        o.x = lt[(s4 + 0) * 66 + ri];
        o.y = lt[(s4 + 1) * 66 + ri];
        o.z = lt[(s4 + 2) * 66 + ri];
        o.w = lt[(s4 + 3) * 66 + ri];
        *(ushort4*)&wqT[(size_t)(c0 + ri) * 1024 + r0 + s4] = o;
    }
}

// ---------------------------------------------------------------------------
// C = A @ B^T. 128x64 tile, BK=32, XOR-swizzled LDS. 256 thr = 4 waves (2Mx2N),
// per-wave 64x32 out. 512 blocks for 1024x1024 GEMMs -> 2/CU resident.
// ---------------------------------------------------------------------------
template <typename OutT>
__global__ __launch_bounds__(256, 4)
void gemm_bt_n64(const ushort_t* __restrict__ A, int lda, long strideA,
                 const ushort_t* __restrict__ B, int ldb, long strideB,
                 OutT* __restrict__ C0, int ldc0, long strideC0, int K)
{
    __shared__ ushort_t lA[128 * 32];
    __shared__ ushort_t lB[64 * 32];

    const int t    = threadIdx.x;
    const int lane = t & 63;
    const int wid  = t >> 6;          // 0..3
    const int z    = blockIdx.z;

    A += (size_t)z * strideA;
    B += (size_t)z * strideB;

    const int m0 = blockIdx.x * 128;
    const int n0 = blockIdx.y * 64;

    const int wm = (wid >> 1) * 64;   // 0,64
    const int wn = (wid & 1) * 32;    // 0,32
    const int mr = lane & 15;
    const int q4 = lane >> 4;

    const int row_a = t >> 2;                       // 0..63
    const int seg   = ((t & 3) ^ ((t >> 3) & 3)) * 8;
    const int csw   = (q4 ^ ((mr >> 1) & 3)) * 16;

    f32x4 acc[4][2] = {};

    for (int k0 = 0; k0 < K; k0 += 32) {
        __syncthreads();
        gld_lds16(A + (size_t)(m0 + row_a) * lda + k0 + seg,      (char*)lA + wid * 1024);
        gld_lds16(A + (size_t)(m0 + 64 + row_a) * lda + k0 + seg, (char*)lA + 4096 + wid * 1024);
        gld_lds16(B + (size_t)(n0 + row_a) * ldb + k0 + seg,      (char*)lB + wid * 1024);
        __syncthreads();

        bf16x8 af[4], bf[2];
#pragma unroll
        for (int i = 0; i < 4; ++i)
            af[i] = *(const bf16x8*)((const char*)lA + (wm + i * 16 + mr) * 64 + csw);
#pragma unroll
        for (int j = 0; j < 2; ++j)
            bf[j] = *(const bf16x8*)((const char*)lB + (wn + j * 16 + mr) * 64 + csw);
#pragma unroll
        for (int i = 0; i < 4; ++i)
#pragma unroll
            for (int j = 0; j < 2; ++j)
                acc[i][j] = __builtin_amdgcn_mfma_f32_16x16x32_bf16(af[i], bf[j], acc[i][j], 0, 0, 0);
    }

    OutT* Cw = C0 + (size_t)z * strideC0;
#pragma unroll
    for (int i = 0; i < 4; ++i) {
        const int rbase = m0 + wm + i * 16 + q4 * 4;
#pragma unroll
        for (int j = 0; j < 2; ++j) {
            const int col = n0 + wn + j * 16 + mr;
#pragma unroll
            for (int r = 0; r < 4; ++r) {
                const float v = acc[i][j][r];
                const size_t off = (size_t)(rbase + r) * ldc0 + col;
                if constexpr (sizeof(OutT) == 2) Cw[off] = f2bf(v);
                else                             Cw[off] = v;
            }
        }
    }
}

// ---------------------------------------------------------------------------
// FINAL GEMM: C = A @ B^T fp32. 256x128 tile, BK=32, 4 waves, wave = 128x64
// (acc[8][4], 32 MFMA / 12 ds_read). TRIPLE-buffered LDS (3x24KB=72KB) ->
// 2 blocks/CU. One s_barrier per kt, counted-vmcnt ledger:
//   prologue stage(0),stage(1), vmcnt(6), BAR.
//   iter kt: rd 12 frags from buf[cur] | stage(kt+2)->buf[cur+2] | lgkm0 |
//            32 MFMA | vmcnt(6) (drain kt+1, leave kt+2) | BAR.
// + XCD-bijective remap (FETCH -14%).
// ---------------------------------------------------------------------------
__global__ __launch_bounds__(256, 2)
void gemm_fin(const ushort_t* __restrict__ A, int lda, long strideA,
              const ushort_t* __restrict__ B, int ldb, long strideB,
              float* __restrict__ C, int ldc, long strideC, int K)
{
    __shared__ char lds[73728];      // 3 x 24576 (A@0..16K, B@16K..24K)

    const int t    = threadIdx.x;    // 256
    const int lane = t & 63;
    const int wid  = t >> 6;         // 0..3

    const int L  = blockIdx.x + (blockIdx.y << 4) + (blockIdx.z << 7);
    const int w  = ((L & 7) << 6) + (L >> 3);
    const int bx = w & 15, by = (w >> 4) & 7, z = w >> 7;

    A += (size_t)z * strideA;
    B += (size_t)z * strideB;

    const int m0 = bx * 256;
    const int n0 = by * 128;

    const int wr = wid >> 1;         // 0..1: 128-row half of A-tile
    const int wn = wid & 1;          // 0..1: 64-col half of B-tile
    const int mr = lane & 15;
    const int q4 = lane >> 4;

    const int NT = K >> 5;           // 32

    const int row_a = t >> 2;                         // 0..63
    const int seg   = ((t & 3) ^ ((t >> 3) & 3)) * 8; // inverse-swizzled src col
    const int csw   = (q4 ^ ((mr >> 1) & 3)) * 16;    // swizzled read col

    auto stage = [&](int tgt, int bsel) {
        if (tgt >= NT) return;
        char* base = lds + bsel * 24576 + wid * 1024;
        const ushort_t* gA = A + (size_t)(m0 + row_a) * lda + tgt * 32 + seg;
        gld_lds16(gA,                          base);          // rows   0..63
        gld_lds16(gA + ((size_t)lda << 6),     base + 4096);   // rows  64..127
        gld_lds16(gA + ((size_t)lda << 7),     base + 8192);   // rows 128..191
        gld_lds16(gA + (size_t)lda * 192,      base + 12288);  // rows 192..255
        const ushort_t* gB = B + (size_t)(n0 + row_a) * ldb + tgt * 32 + seg;
        gld_lds16(gB,                          base + 16384);  // rows   0..63
        gld_lds16(gB + ((size_t)ldb << 6),     base + 20480);  // rows  64..127
    };

    bf16x8 af[8], bf[4];
    f32x4 acc[8][4] = {};

    // prologue
    stage(0, 0);
    stage(1, 1);
    asm volatile("s_waitcnt vmcnt(6)" ::: "memory");
    __builtin_amdgcn_s_barrier();

    int cur = 0;
    for (int kt = 0; kt < NT; ++kt) {
        const char* buf = lds + cur * 24576;
#pragma unroll
        for (int i = 0; i < 8; ++i)
            af[i] = *(const bf16x8*)(buf + (wr * 128 + i * 16 + mr) * 64 + csw);
#pragma unroll
        for (int j = 0; j < 4; ++j)
            bf[j] = *(const bf16x8*)(buf + 16384 + (wn * 64 + j * 16 + mr) * 64 + csw);

        int b2 = cur + 2; if (b2 >= 3) b2 -= 3;
        stage(kt + 2, b2);

        asm volatile("s_waitcnt lgkmcnt(0)" ::: "memory");
        __builtin_amdgcn_sched_barrier(0);
        __builtin_amdgcn_s_setprio(1);
#pragma unroll
        for (int i = 0; i < 8; ++i)
#pragma unroll
            for (int j = 0; j < 4; ++j)
                acc[i][j] = __builtin_amdgcn_mfma_f32_16x16x32_bf16(
                    af[i], bf[j], acc[i][j], 0, 0, 0);
        __builtin_amdgcn_s_setprio(0);
        __builtin_amdgcn_sched_barrier(0);

        if (kt + 2 < NT)       asm volatile("s_waitcnt vmcnt(6)" ::: "memory");
        else if (kt + 2 == NT) asm volatile("s_waitcnt vmcnt(0)" ::: "memory");
        __builtin_amdgcn_s_barrier();
        if (++cur == 3) cur = 0;
    }

    float* Cw = C + (size_t)z * strideC;
#pragma unroll
    for (int i = 0; i < 8; ++i) {
        const int rbase = m0 + wr * 128 + i * 16 + q4 * 4;
#pragma unroll
        for (int j = 0; j < 4; ++j) {
            const int col = n0 + wn * 64 + j * 16 + mr;
#pragma unroll
            for (int r = 0; r < 4; ++r)
                Cw[(size_t)(rbase + r) * ldc + col] = acc[i][j][r];
        }
    }
}

// ---------------------------------------------------------------------------
// Gram GEMM: 3-buf single-barrier counted-vmcnt ledger at 128^2, 4-load
// stages, vmcnt(4) steady, launch_bounds(256,2). LDS 3x16KB -> 3 blocks/CU.
// grid (16 z fastest, 36 triangle tiles).
// ---------------------------------------------------------------------------
__global__ __launch_bounds__(256, 2)
void gemm_gram3(const ushort_t* __restrict__ X, ushort_t* __restrict__ Gp)
{
    __shared__ char lds[49152];      // 3 x 16384 (A@0..8K, B@8K..16K)

    const int t    = threadIdx.x;
    const int lane = t & 63;
    const int wid  = t >> 6;

    const int z  = blockIdx.x;
    const int bb = z >> 2, ks = z & 3;

    int ti = 0, rem = blockIdx.y;
    while (rem >= 8 - ti) { rem -= 8 - ti; ++ti; }
    const int tj = ti + rem;
    const int m0 = ti * 128;
    const int n0 = tj * 128;

    const ushort_t* A = X + (size_t)bb * 4096 + (size_t)ks * 1024;
    const int NT = 32;               // K = 1024, BK = 32

    const int wm = (wid >> 1) * 64;
    const int wn = (wid & 1) * 64;
    const int mr = lane & 15;
    const int q4 = lane >> 4;

    const int row_a = t >> 2;
    const int seg   = ((t & 3) ^ ((t >> 3) & 3)) * 8;
    const int csw   = (q4 ^ ((mr >> 1) & 3)) * 16;

    auto stage = [&](int tgt, int bsel) {
        if (tgt >= NT) return;
        char* base = lds + bsel * 16384 + wid * 1024;
        const ushort_t* gA = A + (size_t)(m0 + row_a) * 16384 + tgt * 32 + seg;
        gld_lds16(gA,                        base);
        gld_lds16(gA + ((size_t)16384 << 6), base + 4096);
        const ushort_t* gB = A + (size_t)(n0 + row_a) * 16384 + tgt * 32 + seg;
        gld_lds16(gB,                        base + 8192);
        gld_lds16(gB + ((size_t)16384 << 6), base + 12288);
    };

    bf16x8 af[4], bf[4];
    f32x4 acc[4][4] = {};

    stage(0, 0);
    stage(1, 1);
    asm volatile("s_waitcnt vmcnt(4)" ::: "memory");
    __builtin_amdgcn_s_barrier();

    int cur = 0;
    for (int kt = 0; kt < NT; ++kt) {
        const char* buf = lds + cur * 16384;
#pragma unroll
        for (int i = 0; i < 4; ++i)
            af[i] = *(const bf16x8*)(buf + (wm + i * 16 + mr) * 64 + csw);
#pragma unroll
        for (int j = 0; j < 4; ++j)
            bf[j] = *(const bf16x8*)(buf + 8192 + (wn + j * 16 + mr) * 64 + csw);

        int b2 = cur + 2; if (b2 >= 3) b2 -= 3;
        stage(kt + 2, b2);

        asm volatile("s_waitcnt lgkmcnt(0)" ::: "memory");
        __builtin_amdgcn_sched_barrier(0);
        __builtin_amdgcn_s_setprio(1);
#pragma unroll
        for (int i = 0; i < 4; ++i)
#pragma unroll
            for (int j = 0; j < 4; ++j)
                acc[i][j] = __builtin_amdgcn_mfma_f32_16x16x32_bf16(
                    af[i], bf[j], acc[i][j], 0, 0, 0);
        __builtin_amdgcn_s_setprio(0);
        __builtin_amdgcn_sched_barrier(0);

        if (kt + 2 < NT)       asm volatile("s_waitcnt vmcnt(4)" ::: "memory");
        else if (kt + 2 == NT) asm volatile("s_waitcnt vmcnt(0)" ::: "memory");
        __builtin_amdgcn_s_barrier();
        if (++cur == 3) cur = 0;
    }

    ushort_t* Cw = Gp + ((size_t)z << 20);
#pragma unroll
    for (int i = 0; i < 4; ++i) {
        const int rbase = m0 + wm + i * 16 + q4 * 4;
#pragma unroll
        for (int j = 0; j < 4; ++j) {
            const int col = n0 + wn + j * 16 + mr;
#pragma unroll
            for (int r = 0; r < 4; ++r)
                Cw[(size_t)(rbase + r) * 1024 + col] = f2bf(acc[i][j][r]);
        }
    }
}

// ---------------------------------------------------------------------------
// reduce_g_t: G[b][tr*64+r][tc*64+c] = sum_ks Gp[b*4+ks] at source 64-tile
// (sr,sc)=(min,max). Lower tiles transpose through LDS (pitch 65).
// ---------------------------------------------------------------------------
__global__ __launch_bounds__(256)
void reduce_g_t(const ushort_t* __restrict__ Gp, ushort_t* __restrict__ G)
{
    __shared__ float acc[64 * 65];

    const int t  = threadIdx.x;
    const int b  = blockIdx.y;
    const int tr = blockIdx.x >> 4, tc = blockIdx.x & 15;
    const int sr = (tr <= tc) ? tr : tc;
    const int sc = (tr <= tc) ? tc : tr;
    const bool flip = tr > tc;

#pragma unroll
    for (int p = 0; p < 4; ++p) {
        const int idx = p * 256 + t;
        const int r = idx >> 4, c = (idx & 15) * 4;
        float a0 = 0.f, a1 = 0.f, a2 = 0.f, a3 = 0.f;
#pragma unroll
        for (int ksl = 0; ksl < 4; ++ksl) {
            const ushort4 u = *(const ushort4*)&Gp[((size_t)(b * 4 + ksl) << 20)
                                                   + (size_t)(sr * 64 + r) * 1024 + sc * 64 + c];
            a0 += bf2f(u.x); a1 += bf2f(u.y); a2 += bf2f(u.z); a3 += bf2f(u.w);
        }
        acc[r * 65 + c + 0] = a0;
        acc[r * 65 + c + 1] = a1;
        acc[r * 65 + c + 2] = a2;
        acc[r * 65 + c + 3] = a3;
    }
    __syncthreads();

#pragma unroll
    for (int p = 0; p < 4; ++p) {
        const int idx = p * 256 + t;
        const int r = idx >> 4, c = (idx & 15) * 4;
        float v0, v1, v2, v3;
        if (flip) {
            v0 = acc[(c + 0) * 65 + r];
            v1 = acc[(c + 1) * 65 + r];
            v2 = acc[(c + 2) * 65 + r];
            v3 = acc[(c + 3) * 65 + r];
        } else {
            v0 = acc[r * 65 + c + 0];
            v1 = acc[r * 65 + c + 1];
            v2 = acc[r * 65 + c + 2];
            v3 = acc[r * 65 + c + 3];
        }
        ushort4 o;
        o.x = f2bf(v0); o.y = f2bf(v1); o.z = f2bf(v2); o.w = f2bf(v3);
        *(ushort4*)&G[((size_t)b << 20) + (size_t)(tr * 64 + r) * 1024 + tc * 64 + c] = o;
    }
}

// ---------------------------------------------------------------------------
// kv partials: KVp[is][bh][d][e] = sum_{i-slice} H[b][h64+d][i]*Wv[h64+e][i]
// ---------------------------------------------------------------------------
__global__ __launch_bounds__(256)
void kvblk(const ushort_t* __restrict__ H, const ushort_t* __restrict__ Wv,
           float* __restrict__ KVp)
{
    __shared__ ushort_t sH[64 * 132];
    __shared__ ushort_t sV[64 * 132];

    const int t  = threadIdx.x;
    const int is = blockIdx.x;
    const int bh = blockIdx.y;
    const int b  = bh >> 4, h = bh & 15;

    const ushort_t* Hp = H + ((size_t)b << 20) + (size_t)(h * 64) * 1024 + is * 128;
    const ushort_t* Vp = Wv + (size_t)(h * 64) * 1024 + is * 128;

#pragma unroll
    for (int i2 = 0; i2 < 8; ++i2) {
        const int ci = i2 * 256 + t;
        const int r = ci >> 5, c = (ci & 31) * 4;
        *(uint2*)&sH[r * 132 + c] = *(const uint2*)&Hp[(size_t)r * 1024 + c];
        *(uint2*)&sV[r * 132 + c] = *(const uint2*)&Vp[(size_t)r * 1024 + c];
    }
    __syncthreads();

    const int d0 = (t >> 4) * 4;
    const int e0 = (t & 15) * 4;
    float acc[4][4] = {};

#pragma unroll 2
    for (int i4 = 0; i4 < 128; i4 += 4) {
        uint2 hu[4], vu[4];
#pragma unroll
        for (int j = 0; j < 4; ++j) {
            hu[j] = *(const uint2*)&sH[(d0 + j) * 132 + i4];
            vu[j] = *(const uint2*)&sV[(e0 + j) * 132 + i4];
        }
        float hf[4][4], vf[4][4];
#pragma unroll
        for (int j = 0; j < 4; ++j) {
            hf[j][0] = __uint_as_float(hu[j].x << 16);
            hf[j][1] = __uint_as_float(hu[j].x & 0xffff0000u);
            hf[j][2] = __uint_as_float(hu[j].y << 16);
            hf[j][3] = __uint_as_float(hu[j].y & 0xffff0000u);
            vf[j][0] = __uint_as_float(vu[j].x << 16);
            vf[j][1] = __uint_as_float(vu[j].x & 0xffff0000u);
            vf[j][2] = __uint_as_float(vu[j].y << 16);
            vf[j][3] = __uint_as_float(vu[j].y & 0xffff0000u);
        }
#pragma unroll
        for (int ii = 0; ii < 4; ++ii)
#pragma unroll
            for (int di = 0; di < 4; ++di)
#pragma unroll
                for (int ej = 0; ej < 4; ++ej)
                    acc[di][ej] += hf[di][ii] * vf[ej][ii];
    }

    float* outp = KVp + ((size_t)(is * 64 + bh)) * 4096;
#pragma unroll
    for (int i = 0; i < 4; ++i) {
        float4 o; o.x = acc[i][0]; o.y = acc[i][1]; o.z = acc[i][2]; o.w = acc[i][3];
        *(float4*)&outp[(d0 + i) * 64 + e0] = o;
    }
}

// ---------------------------------------------------------------------------
// make_E8: E_t[b][j][h*64+d] = scale * sum_e kv[b,h,d,e] * W_o[j, h*64+e]
// kv summed from the 8 kvblk partials during staging.
// ---------------------------------------------------------------------------
__global__ __launch_bounds__(256)
void make_E8(const float* __restrict__ KVp, const float* __restrict__ Wo,
             ushort_t* __restrict__ Et)
{
    __shared__ float skv[64 * 65];
    __shared__ float swo[64 * 65];

    const int t  = threadIdx.x;
    const int bh = blockIdx.y;
    const int b  = bh >> 4, h = bh & 15;
    const int j0 = blockIdx.x * 64;

#pragma unroll
    for (int i = 0; i < 4; ++i) {
        const int idx = t + i * 256;
        const int r = idx >> 4, c = (idx & 15) * 4;
        float4 f; f.x = 0.f; f.y = 0.f; f.z = 0.f; f.w = 0.f;
#pragma unroll
        for (int is = 0; is < 8; ++is) {
            const float4 p = *(const float4*)&KVp[((size_t)(is * 64 + bh)) * 4096
                                                  + r * 64 + c];
            f.x += p.x; f.y += p.y; f.z += p.z; f.w += p.w;
        }
        skv[r * 65 + c + 0] = f.x;
        skv[r * 65 + c + 1] = f.y;
        skv[r * 65 + c + 2] = f.z;
        skv[r * 65 + c + 3] = f.w;
        const float4 g = *(const float4*)&Wo[(size_t)(j0 + r) * 1024 + h * 64 + c];
        swo[r * 65 + c + 0] = g.x;
        swo[r * 65 + c + 1] = g.y;
        swo[r * 65 + c + 2] = g.z;
        swo[r * 65 + c + 3] = g.w;
    }
    __syncthreads();

    const int d0 = (t & 15) * 4;
#pragma unroll
    for (int pass = 0; pass < 4; ++pass) {
        const int jloc = (t >> 4) + pass * 16;
        float s0 = 0.f, s1 = 0.f, s2 = 0.f, s3 = 0.f;
        const float* wrow = &swo[jloc * 65];
#pragma unroll 8
        for (int e = 0; e < 64; ++e) {
            const float w = wrow[e];
            s0 += skv[(d0 + 0) * 65 + e] * w;
            s1 += skv[(d0 + 1) * 65 + e] * w;
            s2 += skv[(d0 + 2) * 65 + e] * w;
            s3 += skv[(d0 + 3) * 65 + e] * w;
        }
        ushort4 o;
        o.x = f2bf(s0 * 0.125f);
        o.y = f2bf(s1 * 0.125f);
        o.z = f2bf(s2 * 0.125f);
        o.w = f2bf(s3 * 0.125f);
        *(ushort4*)&Et[((size_t)b * 1024 + j0 + jloc) * 1024 + h * 64 + d0] = o;
    }
}

// ---------------------------------------------------------------------------

extern "C" void kernel_launch(void* const* d_in, const int* in_sizes, int n_in,
                              void* d_out, int out_size, void* d_ws, size_t ws_size,
                              hipStream_t stream)
{
    const float* x  = (const float*)d_in[0];
    const float* Wq = (const float*)d_in[1];
    const float* Wk = (const float*)d_in[2];
    const float* Wv = (const float*)d_in[3];
    const float* Wo = (const float*)d_in[4];
    float* out = (float*)d_out;

    const int B = 4, S = 4096, D = 1024;
    const long MB1 = 1048576;

    char* ws = (char*)d_ws;
    size_t off = 0;
    auto alloc = [&](size_t bytes) -> void* {
        void* p = ws + off;
        off += (bytes + 255) & ~(size_t)255;
        return p;
    };
    ushort_t* xb   = (ushort_t*)alloc((size_t)B * S * D * 2);      // 33.5 MB
    ushort_t* xbT  = (ushort_t*)alloc((size_t)D * B * S * 2);      // 33.5 MB
    ushort_t* wkv  = (ushort_t*)alloc((size_t)2 * D * D * 2);      // wk | wv
    ushort_t* wqT  = (ushort_t*)alloc((size_t)D * D * 2);
    ushort_t* Gb   = (ushort_t*)alloc((size_t)B * D * D * 2);      // 8.4 MB
    float*    kvp  = (float*)alloc((size_t)8 * 64 * 4096 * 4);     // 8.4 MB
    ushort_t* Fb   = (ushort_t*)alloc((size_t)B * D * D * 2);      // 8.4 MB
    char*     R1   = (char*)alloc((size_t)16 * MB1 * 2);           // 33.5 MB shared
    ushort_t* Gp = (ushort_t*)R1;                    // [16][1M] bf16 partials
    ushort_t* Hb = (ushort_t*)R1;                    // [4][1M] (Gp[0..7] dead after reduce)
    ushort_t* Et = (ushort_t*)(R1 + 8 * MB1 * 2);    // [4][1M] (Gp[8..15] dead after reduce)
    ushort_t* wkb = wkv;
    ushort_t* wvb = wkv + MB1;

    // all input casts in one dispatch (write-contiguity layout)
    prep<<<dim3(2560), dim3(256), 0, stream>>>(x, Wk, Wv, Wq, xb, xbT, wkv, wqT);

    // G[b] = x^T x, symmetric: 36 upper-triangle 128-tiles, split-K=4, z fastest
    gemm_gram3<<<dim3(16, 36), dim3(256), 0, stream>>>(xbT, Gp);
    reduce_g_t<<<dim3(256, 4), dim3(256), 0, stream>>>(Gp, Gb);

    // H[b] = Wk @ G[b]  (G symmetric -> use as B directly); 512 blocks, 2/CU
    gemm_bt_n64<ushort_t><<<dim3(8, 16, 4), dim3(256), 0, stream>>>(
        wkb, D, 0, Gb, D, MB1, Hb, D, MB1, D);

    // kv[b,h] = H_h @ Wv_h^T (i-split 8 partials)
    kvblk<<<dim3(8, 64), dim3(256), 0, stream>>>(Hb, wvb, kvp);

    // E_t (sums the 8 partials inline)
    make_E8<<<dim3(16, 64), dim3(256), 0, stream>>>(kvp, Wo, Et);

    // F[b] = E_t[b] @ Wq; 512 blocks, 2/CU
    gemm_bt_n64<ushort_t><<<dim3(8, 16, 4), dim3(256), 0, stream>>>(
        Et, D, MB1, wqT, D, 0, Fb, D, (long)D * D, D);

    // out[b] = x[b] @ F[b]^T -> fp32: 256x128 3-buf + XCD remap
    gemm_fin<<<dim3(16, 8, 4), dim3(256), 0, stream>>>(
        xb, D, (long)S * D, Fb, D, (long)D * D, out, D, (long)S * D, D);
}

// Round 9
// 307.602 us; speedup vs baseline: 1.0108x; 1.0069x over previous
//
#include <hip/hip_runtime.h>
#include <hip/hip_bf16.h>
#include <cstdint>

// ---------------------------------------------------------------------------
// LinearMultiHeadAttention: B=4, S=4096, D_MODEL=1024, H=16, Dk=64
// Gram-path:
//   G[b]  = x[b]^T x[b]     (SYMMETRIC: upper-triangle tiles only, split-K=4)
//   H[b]  = Wk @ G[b]
//   kv[b,h] = H_h @ Wv_h^T
//   E_t[b][j][hd] = scale*sum_e kv*Wo
//   F[b]  = E_t[b] @ Wq
//   out   = x @ F[b]^T
// R15 vs R14: prep v5 -- SINGLE-READ full-LDS transpose tile. R14's Role B
// read x in 128B chunks at 4KB stride (page thrash moved to read side) and
// read x twice (FETCH 39->71.5MB). Now ONE role covers [256s x 256D] with a
// 128KiB LDS tile (proven static size):
//   reads:  1KB contiguous per row, x read ONCE (grid 256 = 1/CU)
//   xb:     512B contiguous runs
//   xbT:    512B contiguous runs (was 128B pre-R14)
//   LDS:    chunk-XOR pc=(i>>3)^((s>>4)&31): phase-1 b128 writes ~4-way,
//           phase-2 u16 column reads ~2-4-way (both cheap per m136)
// Roles C (Wk/Wv cast) and D (Wq transpose) unchanged, ids 256..767.
// Everything else byte-identical to R14.
// ---------------------------------------------------------------------------

typedef __bf16 bf16x8 __attribute__((ext_vector_type(8)));
typedef float f32x4 __attribute__((ext_vector_type(4)));
typedef unsigned short ushort_t;
typedef unsigned short ushort8_t __attribute__((ext_vector_type(8)));

__device__ inline void gld_lds16(const void* g, void* l) {
    __builtin_amdgcn_global_load_lds(
        (const __attribute__((address_space(1))) unsigned int*)g,
        (__attribute__((address_space(3))) unsigned int*)l,
        16, 0, 0);
}

__device__ inline ushort_t f2bf(float f) {
    uint32_t u = __float_as_uint(f);
    uint32_t r = (u + 0x7fffu + ((u >> 16) & 1u)) >> 16;
    return (ushort_t)r;
}
__device__ inline float bf2f(ushort_t u) {
    return __uint_as_float((uint32_t)u << 16);
}

// ---------------------------------------------------------------------------
// prep v5 (grid 768): role X [0,256) x->xb+xbT; C [256,512) Wk|Wv; D [512,768)
// ---------------------------------------------------------------------------
__global__ __launch_bounds__(256)
void prep(const float* __restrict__ x, const float* __restrict__ Wk,
          const float* __restrict__ Wv, const float* __restrict__ Wq,
          ushort_t* __restrict__ xb, ushort_t* __restrict__ xbT,
          ushort_t* __restrict__ wkv, ushort_t* __restrict__ wqT)
{
    __shared__ ushort_t lt[256 * 256];   // 128 KiB; roles C/D reuse the head
    const int id = blockIdx.x;
    const int t  = threadIdx.x;

    if (id < 256) {
        // ---- Role X: [256s x 256D] tile -> xb + xbT ----
        const int s0 = (id & 63) * 256;
        const int i0 = (id >> 6) * 256;
        // logical lt[s][i] at element index; chunk-XOR for bank spread
        auto lidx = [&](int s, int i) -> int {
            return s * 256 + ((((i >> 3) ^ ((s >> 4) & 31)) << 3) | (i & 7));
        };

        // phase 1: read 1KB rows, convert, write xb (512B runs) + LDS
        for (int c = 0; c < 16; ++c) {
            const int slot = c * 256 + t;
            const int sr = slot >> 4;           // 0..255 (16 lanes share row)
            const int fc = (slot & 15) * 16;    // 0..240
            const float* xp = &x[(size_t)(s0 + sr) * 1024 + i0 + fc];
            const float4 a = *(const float4*)(xp);
            const float4 b = *(const float4*)(xp + 4);
            const float4 d = *(const float4*)(xp + 8);
            const float4 e = *(const float4*)(xp + 12);
            ushort8_t o0, o1;
            o0[0] = f2bf(a.x); o0[1] = f2bf(a.y); o0[2] = f2bf(a.z); o0[3] = f2bf(a.w);
            o0[4] = f2bf(b.x); o0[5] = f2bf(b.y); o0[6] = f2bf(b.z); o0[7] = f2bf(b.w);
            o1[0] = f2bf(d.x); o1[1] = f2bf(d.y); o1[2] = f2bf(d.z); o1[3] = f2bf(d.w);
            o1[4] = f2bf(e.x); o1[5] = f2bf(e.y); o1[6] = f2bf(e.z); o1[7] = f2bf(e.w);
            ushort_t* xo = &xb[(size_t)(s0 + sr) * 1024 + i0 + fc];
            *(ushort8_t*)(xo)     = o0;
            *(ushort8_t*)(xo + 8) = o1;
            *(ushort8_t*)&lt[lidx(sr, fc)]     = o0;
            *(ushort8_t*)&lt[lidx(sr, fc + 8)] = o1;
        }
        __syncthreads();

        // phase 2: column-gather from LDS, write xbT in 512B runs
        for (int c = 0; c < 16; ++c) {
            const int slot = c * 256 + t;
            const int ir = slot >> 4;           // xbT row (D) 0..255
            const int sc = (slot & 15) * 16;    // s offset 0..240
            ushort8_t o0, o1;
#pragma unroll
            for (int k = 0; k < 8; ++k)
                o0[k] = lt[lidx(sc + k, ir)];
#pragma unroll
            for (int k = 0; k < 8; ++k)
                o1[k] = lt[lidx(sc + 8 + k, ir)];
            ushort_t* to = &xbT[(size_t)(i0 + ir) * 16384 + s0 + sc];
            *(ushort8_t*)(to)     = o0;
            *(ushort8_t*)(to + 8) = o1;
        }
        return;
    }

    if (id < 512) {
        // ---- Role C: Wk/Wv plain cast, 8192 floats/block ----
        const int q  = id - 256;                // 0..255
        const int qq = (q < 128) ? q : q - 128;
        const float* src = (q < 128) ? Wk : Wv;
        float4 f[8];
#pragma unroll
        for (int c = 0; c < 8; ++c)
            f[c] = *(const float4*)&src[(size_t)qq * 8192 + c * 1024 + t * 4];
        ushort_t* d = wkv + (size_t)q * 8192;
#pragma unroll
        for (int c = 0; c < 8; ++c) {
            ushort4 o;
            o.x = f2bf(f[c].x); o.y = f2bf(f[c].y);
            o.z = f2bf(f[c].z); o.w = f2bf(f[c].w);
            *(ushort4*)&d[c * 1024 + t * 4] = o;
        }
        return;
    }

    // ---- Role D: Wq transpose (64x64 tile, 66-pitch in lt head) ----
    const int id2 = id - 512;                   // 0..255
    const int r0 = (id2 >> 4) * 64;
    const int c0 = (id2 & 15) * 64;
    float4 f[4];
#pragma unroll
    for (int c = 0; c < 4; ++c) {
        const int idx = c * 256 + t;
        const int r = idx >> 4, c4 = (idx & 15) * 4;
        f[c] = *(const float4*)&Wq[(size_t)(r0 + r) * 1024 + c0 + c4];
    }
#pragma unroll
    for (int c = 0; c < 4; ++c) {
        const int idx = c * 256 + t;
        const int r = idx >> 4, c4 = (idx & 15) * 4;
        ushort4 o;
        o.x = f2bf(f[c].x); o.y = f2bf(f[c].y);
        o.z = f2bf(f[c].z); o.w = f2bf(f[c].w);
        *(uint32_t*)&lt[r * 66 + c4]     = (uint32_t)o.x | ((uint32_t)o.y << 16);
        *(uint32_t*)&lt[r * 66 + c4 + 2] = (uint32_t)o.z | ((uint32_t)o.w << 16);
    }
    __syncthreads();
#pragma unroll
    for (int c = 0; c < 4; ++c) {
        const int idx = c * 256 + t;
        const int ri = idx >> 4, s4 = (idx & 15) * 4;
        ushort4 o;
        o.x = lt[(s4 + 0) * 66 + ri];
        o.y = lt[(s4 + 1) * 66 + ri];
        o.z = lt[(s4 + 2) * 66 + ri];
        o.w = lt[(s4 + 3) * 66 + ri];
        *(ushort4*)&wqT[(size_t)(c0 + ri) * 1024 + r0 + s4] = o;
    }
}

// ---------------------------------------------------------------------------
// C = A @ B^T. 128x64 tile, BK=32, XOR-swizzled LDS. 256 thr = 4 waves (2Mx2N),
// per-wave 64x32 out. 512 blocks for 1024x1024 GEMMs -> 2/CU resident.
// ---------------------------------------------------------------------------
template <typename OutT>
__global__ __launch_bounds__(256, 4)
void gemm_bt_n64(const ushort_t* __restrict__ A, int lda, long strideA,
                 const ushort_t* __restrict__ B, int ldb, long strideB,
                 OutT* __restrict__ C0, int ldc0, long strideC0, int K)
{
    __shared__ ushort_t lA[128 * 32];
    __shared__ ushort_t lB[64 * 32];

    const int t    = threadIdx.x;
    const int lane = t & 63;
    const int wid  = t >> 6;          // 0..3
    const int z    = blockIdx.z;

    A += (size_t)z * strideA;
    B += (size_t)z * strideB;

    const int m0 = blockIdx.x * 128;
    const int n0 = blockIdx.y * 64;

    const int wm = (wid >> 1) * 64;   // 0,64
    const int wn = (wid & 1) * 32;    // 0,32
    const int mr = lane & 15;
    const int q4 = lane >> 4;

    const int row_a = t >> 2;                       // 0..63
    const int seg   = ((t & 3) ^ ((t >> 3) & 3)) * 8;
    const int csw   = (q4 ^ ((mr >> 1) & 3)) * 16;

    f32x4 acc[4][2] = {};

    for (int k0 = 0; k0 < K; k0 += 32) {
        __syncthreads();
        gld_lds16(A + (size_t)(m0 + row_a) * lda + k0 + seg,      (char*)lA + wid * 1024);
        gld_lds16(A + (size_t)(m0 + 64 + row_a) * lda + k0 + seg, (char*)lA + 4096 + wid * 1024);
        gld_lds16(B + (size_t)(n0 + row_a) * ldb + k0 + seg,      (char*)lB + wid * 1024);
        __syncthreads();

        bf16x8 af[4], bf[2];
#pragma unroll
        for (int i = 0; i < 4; ++i)
            af[i] = *(const bf16x8*)((const char*)lA + (wm + i * 16 + mr) * 64 + csw);
#pragma unroll
        for (int j = 0; j < 2; ++j)
            bf[j] = *(const bf16x8*)((const char*)lB + (wn + j * 16 + mr) * 64 + csw);
#pragma unroll
        for (int i = 0; i < 4; ++i)
#pragma unroll
            for (int j = 0; j < 2; ++j)
                acc[i][j] = __builtin_amdgcn_mfma_f32_16x16x32_bf16(af[i], bf[j], acc[i][j], 0, 0, 0);
    }

    OutT* Cw = C0 + (size_t)z * strideC0;
#pragma unroll
    for (int i = 0; i < 4; ++i) {
        const int rbase = m0 + wm + i * 16 + q4 * 4;
#pragma unroll
        for (int j = 0; j < 2; ++j) {
            const int col = n0 + wn + j * 16 + mr;
#pragma unroll
            for (int r = 0; r < 4; ++r) {
                const float v = acc[i][j][r];
                const size_t off = (size_t)(rbase + r) * ldc0 + col;
                if constexpr (sizeof(OutT) == 2) Cw[off] = f2bf(v);
                else                             Cw[off] = v;
            }
        }
    }
}

// ---------------------------------------------------------------------------
// FINAL GEMM: C = A @ B^T fp32. 256x128 tile, BK=32, 4 waves, wave = 128x64
// (acc[8][4], 32 MFMA / 12 ds_read). TRIPLE-buffered LDS (3x24KB=72KB) ->
// 2 blocks/CU. One s_barrier per kt, counted-vmcnt ledger:
//   prologue stage(0),stage(1), vmcnt(6), BAR.
//   iter kt: rd 12 frags from buf[cur] | stage(kt+2)->buf[cur+2] | lgkm0 |
//            32 MFMA | vmcnt(6) (drain kt+1, leave kt+2) | BAR.
// + XCD-bijective remap (FETCH -14%).
// ---------------------------------------------------------------------------
__global__ __launch_bounds__(256, 2)
void gemm_fin(const ushort_t* __restrict__ A, int lda, long strideA,
              const ushort_t* __restrict__ B, int ldb, long strideB,
              float* __restrict__ C, int ldc, long strideC, int K)
{
    __shared__ char lds[73728];      // 3 x 24576 (A@0..16K, B@16K..24K)

    const int t    = threadIdx.x;    // 256
    const int lane = t & 63;
    const int wid  = t >> 6;         // 0..3

    const int L  = blockIdx.x + (blockIdx.y << 4) + (blockIdx.z << 7);
    const int w  = ((L & 7) << 6) + (L >> 3);
    const int bx = w & 15, by = (w >> 4) & 7, z = w >> 7;

    A += (size_t)z * strideA;
    B += (size_t)z * strideB;

    const int m0 = bx * 256;
    const int n0 = by * 128;

    const int wr = wid >> 1;         // 0..1: 128-row half of A-tile
    const int wn = wid & 1;          // 0..1: 64-col half of B-tile
    const int mr = lane & 15;
    const int q4 = lane >> 4;

    const int NT = K >> 5;           // 32

    const int row_a = t >> 2;                         // 0..63
    const int seg   = ((t & 3) ^ ((t >> 3) & 3)) * 8; // inverse-swizzled src col
    const int csw   = (q4 ^ ((mr >> 1) & 3)) * 16;    // swizzled read col

    auto stage = [&](int tgt, int bsel) {
        if (tgt >= NT) return;
        char* base = lds + bsel * 24576 + wid * 1024;
        const ushort_t* gA = A + (size_t)(m0 + row_a) * lda + tgt * 32 + seg;
        gld_lds16(gA,                          base);          // rows   0..63
        gld_lds16(gA + ((size_t)lda << 6),     base + 4096);   // rows  64..127
        gld_lds16(gA + ((size_t)lda << 7),     base + 8192);   // rows 128..191
        gld_lds16(gA + (size_t)lda * 192,      base + 12288);  // rows 192..255
        const ushort_t* gB = B + (size_t)(n0 + row_a) * ldb + tgt * 32 + seg;
        gld_lds16(gB,                          base + 16384);  // rows   0..63
        gld_lds16(gB + ((size_t)ldb << 6),     base + 20480);  // rows  64..127
    };

    bf16x8 af[8], bf[4];
    f32x4 acc[8][4] = {};

    // prologue
    stage(0, 0);
    stage(1, 1);
    asm volatile("s_waitcnt vmcnt(6)" ::: "memory");
    __builtin_amdgcn_s_barrier();

    int cur = 0;
    for (int kt = 0; kt < NT; ++kt) {
        const char* buf = lds + cur * 24576;
#pragma unroll
        for (int i = 0; i < 8; ++i)
            af[i] = *(const bf16x8*)(buf + (wr * 128 + i * 16 + mr) * 64 + csw);
#pragma unroll
        for (int j = 0; j < 4; ++j)
            bf[j] = *(const bf16x8*)(buf + 16384 + (wn * 64 + j * 16 + mr) * 64 + csw);

        int b2 = cur + 2; if (b2 >= 3) b2 -= 3;
        stage(kt + 2, b2);

        asm volatile("s_waitcnt lgkmcnt(0)" ::: "memory");
        __builtin_amdgcn_sched_barrier(0);
        __builtin_amdgcn_s_setprio(1);
#pragma unroll
        for (int i = 0; i < 8; ++i)
#pragma unroll
            for (int j = 0; j < 4; ++j)
                acc[i][j] = __builtin_amdgcn_mfma_f32_16x16x32_bf16(
                    af[i], bf[j], acc[i][j], 0, 0, 0);
        __builtin_amdgcn_s_setprio(0);
        __builtin_amdgcn_sched_barrier(0);

        if (kt + 2 < NT)       asm volatile("s_waitcnt vmcnt(6)" ::: "memory");
        else if (kt + 2 == NT) asm volatile("s_waitcnt vmcnt(0)" ::: "memory");
        __builtin_amdgcn_s_barrier();
        if (++cur == 3) cur = 0;
    }

    float* Cw = C + (size_t)z * strideC;
#pragma unroll
    for (int i = 0; i < 8; ++i) {
        const int rbase = m0 + wr * 128 + i * 16 + q4 * 4;
#pragma unroll
        for (int j = 0; j < 4; ++j) {
            const int col = n0 + wn * 64 + j * 16 + mr;
#pragma unroll
            for (int r = 0; r < 4; ++r)
                Cw[(size_t)(rbase + r) * ldc + col] = acc[i][j][r];
        }
    }
}

// ---------------------------------------------------------------------------
// Gram GEMM: 3-buf single-barrier counted-vmcnt ledger at 128^2, 4-load
// stages, vmcnt(4) steady, launch_bounds(256,2). LDS 3x16KB -> 3 blocks/CU.
// grid (16 z fastest, 36 triangle tiles).
// ---------------------------------------------------------------------------
__global__ __launch_bounds__(256, 2)
void gemm_gram3(const ushort_t* __restrict__ X, ushort_t* __restrict__ Gp)
{
    __shared__ char lds[49152];      // 3 x 16384 (A@0..8K, B@8K..16K)

    const int t    = threadIdx.x;
    const int lane = t & 63;
    const int wid  = t >> 6;

    const int z  = blockIdx.x;
    const int bb = z >> 2, ks = z & 3;

    int ti = 0, rem = blockIdx.y;
    while (rem >= 8 - ti) { rem -= 8 - ti; ++ti; }
    const int tj = ti + rem;
    const int m0 = ti * 128;
    const int n0 = tj * 128;

    const ushort_t* A = X + (size_t)bb * 4096 + (size_t)ks * 1024;
    const int NT = 32;               // K = 1024, BK = 32

    const int wm = (wid >> 1) * 64;
    const int wn = (wid & 1) * 64;
    const int mr = lane & 15;
    const int q4 = lane >> 4;

    const int row_a = t >> 2;
    const int seg   = ((t & 3) ^ ((t >> 3) & 3)) * 8;
    const int csw   = (q4 ^ ((mr >> 1) & 3)) * 16;

    auto stage = [&](int tgt, int bsel) {
        if (tgt >= NT) return;
        char* base = lds + bsel * 16384 + wid * 1024;
        const ushort_t* gA = A + (size_t)(m0 + row_a) * 16384 + tgt * 32 + seg;
        gld_lds16(gA,                        base);
        gld_lds16(gA + ((size_t)16384 << 6), base + 4096);
        const ushort_t* gB = A + (size_t)(n0 + row_a) * 16384 + tgt * 32 + seg;
        gld_lds16(gB,                        base + 8192);
        gld_lds16(gB + ((size_t)16384 << 6), base + 12288);
    };

    bf16x8 af[4], bf[4];
    f32x4 acc[4][4] = {};

    stage(0, 0);
    stage(1, 1);
    asm volatile("s_waitcnt vmcnt(4)" ::: "memory");
    __builtin_amdgcn_s_barrier();

    int cur = 0;
    for (int kt = 0; kt < NT; ++kt) {
        const char* buf = lds + cur * 16384;
#pragma unroll
        for (int i = 0; i < 4; ++i)
            af[i] = *(const bf16x8*)(buf + (wm + i * 16 + mr) * 64 + csw);
#pragma unroll
        for (int j = 0; j < 4; ++j)
            bf[j] = *(const bf16x8*)(buf + 8192 + (wn + j * 16 + mr) * 64 + csw);

        int b2 = cur + 2; if (b2 >= 3) b2 -= 3;
        stage(kt + 2, b2);

        asm volatile("s_waitcnt lgkmcnt(0)" ::: "memory");
        __builtin_amdgcn_sched_barrier(0);
        __builtin_amdgcn_s_setprio(1);
#pragma unroll
        for (int i = 0; i < 4; ++i)
#pragma unroll
            for (int j = 0; j < 4; ++j)
                acc[i][j] = __builtin_amdgcn_mfma_f32_16x16x32_bf16(
                    af[i], bf[j], acc[i][j], 0, 0, 0);
        __builtin_amdgcn_s_setprio(0);
        __builtin_amdgcn_sched_barrier(0);

        if (kt + 2 < NT)       asm volatile("s_waitcnt vmcnt(4)" ::: "memory");
        else if (kt + 2 == NT) asm volatile("s_waitcnt vmcnt(0)" ::: "memory");
        __builtin_amdgcn_s_barrier();
        if (++cur == 3) cur = 0;
    }

    ushort_t* Cw = Gp + ((size_t)z << 20);
#pragma unroll
    for (int i = 0; i < 4; ++i) {
        const int rbase = m0 + wm + i * 16 + q4 * 4;
#pragma unroll
        for (int j = 0; j < 4; ++j) {
            const int col = n0 + wn + j * 16 + mr;
#pragma unroll
            for (int r = 0; r < 4; ++r)
                Cw[(size_t)(rbase + r) * 1024 + col] = f2bf(acc[i][j][r]);
        }
    }
}

// ---------------------------------------------------------------------------
// reduce_g_t: G[b][tr*64+r][tc*64+c] = sum_ks Gp[b*4+ks] at source 64-tile
// (sr,sc)=(min,max). Lower tiles transpose through LDS (pitch 65).
// ---------------------------------------------------------------------------
__global__ __launch_bounds__(256)
void reduce_g_t(const ushort_t* __restrict__ Gp, ushort_t* __restrict__ G)
{
    __shared__ float acc[64 * 65];

    const int t  = threadIdx.x;
    const int b  = blockIdx.y;
    const int tr = blockIdx.x >> 4, tc = blockIdx.x & 15;
    const int sr = (tr <= tc) ? tr : tc;
    const int sc = (tr <= tc) ? tc : tr;
    const bool flip = tr > tc;

#pragma unroll
    for (int p = 0; p < 4; ++p) {
        const int idx = p * 256 + t;
        const int r = idx >> 4, c = (idx & 15) * 4;
        float a0 = 0.f, a1 = 0.f, a2 = 0.f, a3 = 0.f;
#pragma unroll
        for (int ksl = 0; ksl < 4; ++ksl) {
            const ushort4 u = *(const ushort4*)&Gp[((size_t)(b * 4 + ksl) << 20)
                                                   + (size_t)(sr * 64 + r) * 1024 + sc * 64 + c];
            a0 += bf2f(u.x); a1 += bf2f(u.y); a2 += bf2f(u.z); a3 += bf2f(u.w);
        }
        acc[r * 65 + c + 0] = a0;
        acc[r * 65 + c + 1] = a1;
        acc[r * 65 + c + 2] = a2;
        acc[r * 65 + c + 3] = a3;
    }
    __syncthreads();

#pragma unroll
    for (int p = 0; p < 4; ++p) {
        const int idx = p * 256 + t;
        const int r = idx >> 4, c = (idx & 15) * 4;
        float v0, v1, v2, v3;
        if (flip) {
            v0 = acc[(c + 0) * 65 + r];
            v1 = acc[(c + 1) * 65 + r];
            v2 = acc[(c + 2) * 65 + r];
            v3 = acc[(c + 3) * 65 + r];
        } else {
            v0 = acc[r * 65 + c + 0];
            v1 = acc[r * 65 + c + 1];
            v2 = acc[r * 65 + c + 2];
            v3 = acc[r * 65 + c + 3];
        }
        ushort4 o;
        o.x = f2bf(v0); o.y = f2bf(v1); o.z = f2bf(v2); o.w = f2bf(v3);
        *(ushort4*)&G[((size_t)b << 20) + (size_t)(tr * 64 + r) * 1024 + tc * 64 + c] = o;
    }
}

// ---------------------------------------------------------------------------
// kv partials: KVp[is][bh][d][e] = sum_{i-slice} H[b][h64+d][i]*Wv[h64+e][i]
// ---------------------------------------------------------------------------
__global__ __launch_bounds__(256)
void kvblk(const ushort_t* __restrict__ H, const ushort_t* __restrict__ Wv,
           float* __restrict__ KVp)
{
    __shared__ ushort_t sH[64 * 132];
    __shared__ ushort_t sV[64 * 132];

    const int t  = threadIdx.x;
    const int is = blockIdx.x;
    const int bh = blockIdx.y;
    const int b  = bh >> 4, h = bh & 15;

    const ushort_t* Hp = H + ((size_t)b << 20) + (size_t)(h * 64) * 1024 + is * 128;
    const ushort_t* Vp = Wv + (size_t)(h * 64) * 1024 + is * 128;

#pragma unroll
    for (int i2 = 0; i2 < 8; ++i2) {
        const int ci = i2 * 256 + t;
        const int r = ci >> 5, c = (ci & 31) * 4;
        *(uint2*)&sH[r * 132 + c] = *(const uint2*)&Hp[(size_t)r * 1024 + c];
        *(uint2*)&sV[r * 132 + c] = *(const uint2*)&Vp[(size_t)r * 1024 + c];
    }
    __syncthreads();

    const int d0 = (t >> 4) * 4;
    const int e0 = (t & 15) * 4;
    float acc[4][4] = {};

#pragma unroll 2
    for (int i4 = 0; i4 < 128; i4 += 4) {
        uint2 hu[4], vu[4];
#pragma unroll
        for (int j = 0; j < 4; ++j) {
            hu[j] = *(const uint2*)&sH[(d0 + j) * 132 + i4];
            vu[j] = *(const uint2*)&sV[(e0 + j) * 132 + i4];
        }
        float hf[4][4], vf[4][4];
#pragma unroll
        for (int j = 0; j < 4; ++j) {
            hf[j][0] = __uint_as_float(hu[j].x << 16);
            hf[j][1] = __uint_as_float(hu[j].x & 0xffff0000u);
            hf[j][2] = __uint_as_float(hu[j].y << 16);
            hf[j][3] = __uint_as_float(hu[j].y & 0xffff0000u);
            vf[j][0] = __uint_as_float(vu[j].x << 16);
            vf[j][1] = __uint_as_float(vu[j].x & 0xffff0000u);
            vf[j][2] = __uint_as_float(vu[j].y << 16);
            vf[j][3] = __uint_as_float(vu[j].y & 0xffff0000u);
        }
#pragma unroll
        for (int ii = 0; ii < 4; ++ii)
#pragma unroll
            for (int di = 0; di < 4; ++di)
#pragma unroll
                for (int ej = 0; ej < 4; ++ej)
                    acc[di][ej] += hf[di][ii] * vf[ej][ii];
    }

    float* outp = KVp + ((size_t)(is * 64 + bh)) * 4096;
#pragma unroll
    for (int i = 0; i < 4; ++i) {
        float4 o; o.x = acc[i][0]; o.y = acc[i][1]; o.z = acc[i][2]; o.w = acc[i][3];
        *(float4*)&outp[(d0 + i) * 64 + e0] = o;
    }
}

// ---------------------------------------------------------------------------
// make_E8: E_t[b][j][h*64+d] = scale * sum_e kv[b,h,d,e] * W_o[j, h*64+e]
// kv summed from the 8 kvblk partials during staging.
// ---------------------------------------------------------------------------
__global__ __launch_bounds__(256)
void make_E8(const float* __restrict__ KVp, const float* __restrict__ Wo,
             ushort_t* __restrict__ Et)
{
    __shared__ float skv[64 * 65];
    __shared__ float swo[64 * 65];

    const int t  = threadIdx.x;
    const int bh = blockIdx.y;
    const int b  = bh >> 4, h = bh & 15;
    const int j0 = blockIdx.x * 64;

#pragma unroll
    for (int i = 0; i < 4; ++i) {
        const int idx = t + i * 256;
        const int r = idx >> 4, c = (idx & 15) * 4;
        float4 f; f.x = 0.f; f.y = 0.f; f.z = 0.f; f.w = 0.f;
#pragma unroll
        for (int is = 0; is < 8; ++is) {
            const float4 p = *(const float4*)&KVp[((size_t)(is * 64 + bh)) * 4096
                                                  + r * 64 + c];
            f.x += p.x; f.y += p.y; f.z += p.z; f.w += p.w;
        }
        skv[r * 65 + c + 0] = f.x;
        skv[r * 65 + c + 1] = f.y;
        skv[r * 65 + c + 2] = f.z;
        skv[r * 65 + c + 3] = f.w;
        const float4 g = *(const float4*)&Wo[(size_t)(j0 + r) * 1024 + h * 64 + c];
        swo[r * 65 + c + 0] = g.x;
        swo[r * 65 + c + 1] = g.y;
        swo[r * 65 + c + 2] = g.z;
        swo[r * 65 + c + 3] = g.w;
    }
    __syncthreads();

    const int d0 = (t & 15) * 4;
#pragma unroll
    for (int pass = 0; pass < 4; ++pass) {
        const int jloc = (t >> 4) + pass * 16;
        float s0 = 0.f, s1 = 0.f, s2 = 0.f, s3 = 0.f;
        const float* wrow = &swo[jloc * 65];
#pragma unroll 8
        for (int e = 0; e < 64; ++e) {
            const float w = wrow[e];
            s0 += skv[(d0 + 0) * 65 + e] * w;
            s1 += skv[(d0 + 1) * 65 + e] * w;
            s2 += skv[(d0 + 2) * 65 + e] * w;
            s3 += skv[(d0 + 3) * 65 + e] * w;
        }
        ushort4 o;
        o.x = f2bf(s0 * 0.125f);
        o.y = f2bf(s1 * 0.125f);
        o.z = f2bf(s2 * 0.125f);
        o.w = f2bf(s3 * 0.125f);
        *(ushort4*)&Et[((size_t)b * 1024 + j0 + jloc) * 1024 + h * 64 + d0] = o;
    }
}

// ---------------------------------------------------------------------------

extern "C" void kernel_launch(void* const* d_in, const int* in_sizes, int n_in,
                              void* d_out, int out_size, void* d_ws, size_t ws_size,
                              hipStream_t stream)
{
    const float* x  = (const float*)d_in[0];
    const float* Wq = (const float*)d_in[1];
    const float* Wk = (const float*)d_in[2];
    const float* Wv = (const float*)d_in[3];
    const float* Wo = (const float*)d_in[4];
    float* out = (float*)d_out;

    const int B = 4, S = 4096, D = 1024;
    const long MB1 = 1048576;

    char* ws = (char*)d_ws;
    size_t off = 0;
    auto alloc = [&](size_t bytes) -> void* {
        void* p = ws + off;
        off += (bytes + 255) & ~(size_t)255;
        return p;
    };
    ushort_t* xb   = (ushort_t*)alloc((size_t)B * S * D * 2);      // 33.5 MB
    ushort_t* xbT  = (ushort_t*)alloc((size_t)D * B * S * 2);      // 33.5 MB
    ushort_t* wkv  = (ushort_t*)alloc((size_t)2 * D * D * 2);      // wk | wv
    ushort_t* wqT  = (ushort_t*)alloc((size_t)D * D * 2);
    ushort_t* Gb   = (ushort_t*)alloc((size_t)B * D * D * 2);      // 8.4 MB
    float*    kvp  = (float*)alloc((size_t)8 * 64 * 4096 * 4);     // 8.4 MB
    ushort_t* Fb   = (ushort_t*)alloc((size_t)B * D * D * 2);      // 8.4 MB
    char*     R1   = (char*)alloc((size_t)16 * MB1 * 2);           // 33.5 MB shared
    ushort_t* Gp = (ushort_t*)R1;                    // [16][1M] bf16 partials
    ushort_t* Hb = (ushort_t*)R1;                    // [4][1M] (Gp[0..7] dead after reduce)
    ushort_t* Et = (ushort_t*)(R1 + 8 * MB1 * 2);    // [4][1M] (Gp[8..15] dead after reduce)
    ushort_t* wkb = wkv;
    ushort_t* wvb = wkv + MB1;

    // all input casts in one dispatch (single-read full-LDS transpose)
    prep<<<dim3(768), dim3(256), 0, stream>>>(x, Wk, Wv, Wq, xb, xbT, wkv, wqT);

    // G[b] = x^T x, symmetric: 36 upper-triangle 128-tiles, split-K=4, z fastest
    gemm_gram3<<<dim3(16, 36), dim3(256), 0, stream>>>(xbT, Gp);
    reduce_g_t<<<dim3(256, 4), dim3(256), 0, stream>>>(Gp, Gb);

    // H[b] = Wk @ G[b]  (G symmetric -> use as B directly); 512 blocks, 2/CU
    gemm_bt_n64<ushort_t><<<dim3(8, 16, 4), dim3(256), 0, stream>>>(
        wkb, D, 0, Gb, D, MB1, Hb, D, MB1, D);

    // kv[b,h] = H_h @ Wv_h^T (i-split 8 partials)
    kvblk<<<dim3(8, 64), dim3(256), 0, stream>>>(Hb, wvb, kvp);

    // E_t (sums the 8 partials inline)
    make_E8<<<dim3(16, 64), dim3(256), 0, stream>>>(kvp, Wo, Et);

    // F[b] = E_t[b] @ Wq; 512 blocks, 2/CU
    gemm_bt_n64<ushort_t><<<dim3(8, 16, 4), dim3(256), 0, stream>>>(
        Et, D, MB1, wqT, D, 0, Fb, D, (long)D * D, D);

    // out[b] = x[b] @ F[b]^T -> fp32: 256x128 3-buf + XCD remap
    gemm_fin<<<dim3(16, 8, 4), dim3(256), 0, stream>>>(
        xb, D, (long)S * D, Fb, D, (long)D * D, out, D, (long)S * D, D);
}